// Round 7
// baseline (409.657 us; speedup 1.0000x reference)
//
#include <hip/hip_runtime.h>
#include <stdint.h>
#include <math.h>

#define FIN 128

typedef __attribute__((ext_vector_type(8))) short short8v;
typedef __attribute__((ext_vector_type(4))) float float4v;
typedef __attribute__((ext_vector_type(2))) float float2v;

// ---------------- bf16 helpers ----------------
__device__ __forceinline__ uint32_t f2_to_bf2(float x, float y) {
    uint32_t r;
    asm("v_cvt_pk_bf16_f32 %0, %1, %2" : "=v"(r) : "v"(x), "v"(y));
    return r;
}
__device__ __forceinline__ unsigned short f_to_bf(float x) {
    union { float f; uint32_t i; } a;
    a.f = x;
    uint32_t u = a.i + 0x7FFF + ((a.i >> 16) & 1);
    return (unsigned short)(u >> 16);
}
// acc2[0..7] (+)= 16 fp8 decoded (packed adds)
__device__ __forceinline__ void acc16_fp8_pk(float2v* acc2, uint4 v) {
    uint32_t us[4] = {v.x, v.y, v.z, v.w};
#pragma unroll
    for (int q = 0; q < 4; ++q) {
        acc2[q * 2 + 0] += __builtin_amdgcn_cvt_pk_f32_fp8(us[q], false);
        acc2[q * 2 + 1] += __builtin_amdgcn_cvt_pk_f32_fp8(us[q], true);
    }
}
// acc2[0..3] (+)= 8 fp8 decoded
__device__ __forceinline__ void acc8_fp8_pk(float2v* acc2, uint2 v) {
    acc2[0] += __builtin_amdgcn_cvt_pk_f32_fp8(v.x, false);
    acc2[1] += __builtin_amdgcn_cvt_pk_f32_fp8(v.x, true);
    acc2[2] += __builtin_amdgcn_cvt_pk_f32_fp8(v.y, false);
    acc2[3] += __builtin_amdgcn_cvt_pk_f32_fp8(v.y, true);
}

// DPP cross-lane move on the VALU pipe: quad_perm / row_ror.
// xor1 = quad_perm[1,0,3,2] = 0xB1 ; xor2 = quad_perm[2,3,0,1] = 0x4E
// ror4 = 0x124 ; ror8 = 0x128. Rotation-sum within the 16-lane ring is a
// valid all-lanes reduce over the rotated bit(s).
template <int CTRL>
__device__ __forceinline__ float dppmov(float x) {
    int i = __builtin_bit_cast(int, x);
    int r = __builtin_amdgcn_update_dpp(i, i, CTRL, 0xF, 0xF, false);
    return __builtin_bit_cast(float, r);
}
__device__ __forceinline__ float swz16f(float x) {
    int r = __builtin_amdgcn_ds_swizzle(__builtin_bit_cast(int, x), 0x401F);
    return __builtin_bit_cast(float, r);
}

__device__ __forceinline__ int edge_at(const void* ei, long long idx, int is32) {
    return is32 ? ((const int*)ei)[idx] : (int)((const long long*)ei)[idx];
}

// ---------------- Level-1 split (16 super-bins, dst>>13) + fused W-conv ----------
// record = (src<<13)|(dst&8191), 30 bits (requires n < 2^19; here n = 100000)
// Blocks [nA, nA+20) run the weight->fragment-ordered bf16 conversion instead.
#define SP_CHUNK 4096
__global__ __launch_bounds__(256) void splitA_kernel(
        const void* __restrict__ ei, int* __restrict__ gCnt,
        uint32_t* __restrict__ buf1, int E, int capS, int nA,
        const float* __restrict__ W1, const float* __restrict__ W2,
        const float* __restrict__ W3, unsigned short* __restrict__ Wf1,
        unsigned short* __restrict__ Wf2, unsigned short* __restrict__ Wf3) {
    __shared__ int hist[16];
    __shared__ int gbase[16];
    __shared__ int lflag;
    int t = threadIdx.x;
    if (blockIdx.x >= nA) {
        // ---- fused wconv ----
        int idx = (blockIdx.x - nA) * 256 + t;
        const float* W;
        unsigned short* Wf;
        int NCOL, base;
        if (idx < 2048)      { W = W1; Wf = Wf1; NCOL = 128; base = idx; }
        else if (idx < 4096) { W = W2; Wf = Wf2; NCOL = 128; base = idx - 2048; }
        else if (idx < 5120) { W = W3; Wf = Wf3; NCOL = 64;  base = idx - 4096; }
        else return;
        int f = base >> 6, l = base & 63;
        int ct = f >> 2, ks = f & 3;
        int nn = ct * 16 + (l & 15);
        int k0 = ks * 32 + (l >> 4) * 8;
        uint32_t pk[4];
#pragma unroll
        for (int j = 0; j < 4; ++j) {
            float a = W[(size_t)(k0 + 2 * j) * NCOL + nn];
            float b = W[(size_t)(k0 + 2 * j + 1) * NCOL + nn];
            pk[j] = f2_to_bf2(a, b);
        }
        ((uint4*)Wf)[base] = make_uint4(pk[0], pk[1], pk[2], pk[3]);
        return;
    }
    if (t < 16) hist[t] = 0;
    if (t == 0) lflag = 0;
    long long base = (long long)blockIdx.x * SP_CHUNK;
    __syncthreads();
    {
        long long e = base + t;
        if (e < E && ((const int*)ei)[2 * e + 1] != 0) atomicOr(&lflag, 1);
    }
    __syncthreads();
    int is32 = lflag;
    uint32_t lrec[16], rec[16];
#pragma unroll
    for (int j = 0; j < 16; ++j) {
        long long e = base + t + j * 256;
        if (e < E) {
            int s = edge_at(ei, e, is32);
            int d = edge_at(ei, (long long)E + e, is32);
            int b = d >> 13;
            int lofs = atomicAdd(&hist[b], 1);
            lrec[j] = ((uint32_t)lofs << 4) | (uint32_t)b;
            rec[j] = ((uint32_t)s << 13) | (uint32_t)(d & 8191);
        } else
            lrec[j] = 0xFFFFFFFFu;
    }
    __syncthreads();
    if (t < 16) gbase[t] = atomicAdd(&gCnt[t], hist[t]);
    __syncthreads();
#pragma unroll
    for (int j = 0; j < 16; ++j) {
        if (lrec[j] != 0xFFFFFFFFu) {
            int b = lrec[j] & 15;
            int pos = gbase[b] + (int)(lrec[j] >> 4);
            if (pos < capS) buf1[(size_t)b * capS + pos] = rec[j];
        }
    }
}

// ---------------- Level-2 split: 128 sub-bins, LDS counting sort ----------------
__global__ __launch_bounds__(256) void splitB_kernel(const int* __restrict__ gCnt,
                                                     const uint32_t* __restrict__ buf1,
                                                     int* __restrict__ cnt2,
                                                     uint32_t* __restrict__ buf2,
                                                     int capS, int cap2, int NB) {
    __shared__ int hist[128];
    __shared__ int sbase[128];
    __shared__ int gbase[128];
    __shared__ uint32_t ordrec[SP_CHUNK];
    __shared__ unsigned char ordsub[SP_CHUNK];
    int t = threadIdx.x;
    int s = blockIdx.y;
    if (t < 128) hist[t] = 0;
    __syncthreads();
    int m = gCnt[s];
    if (m > capS) m = capS;
    long long base = (long long)blockIdx.x * SP_CHUNK;
    uint32_t lrec[16], r32[16];
#pragma unroll
    for (int j = 0; j < 16; ++j) {
        long long i = base + t + j * 256;
        if (i < m) {
            uint32_t r = buf1[(size_t)s * capS + i];
            int d13 = (int)(r & 8191u);
            int sub = d13 >> 6;
            int lofs = atomicAdd(&hist[sub], 1);
            lrec[j] = ((uint32_t)lofs << 7) | (uint32_t)sub;
            r32[j] = ((r >> 13) << 6) | (uint32_t)(d13 & 63);
        } else
            lrec[j] = 0xFFFFFFFFu;
    }
    __syncthreads();
    if (t < 128) sbase[t] = hist[t];
    __syncthreads();
    for (int off = 1; off < 128; off <<= 1) {
        int v = 0;
        if (t < 128 && t >= off) v = sbase[t - off];
        __syncthreads();
        if (t < 128) sbase[t] += v;
        __syncthreads();
    }
    if (t < 128) {
        int g = s * 128 + t;
        gbase[t] = (g < NB && hist[t] > 0) ? atomicAdd(&cnt2[g], hist[t]) : 0;
        sbase[t] -= hist[t];  // exclusive scan
    }
    __syncthreads();
#pragma unroll
    for (int j = 0; j < 16; ++j) {
        if (lrec[j] != 0xFFFFFFFFu) {
            int sub = lrec[j] & 127;
            int pos = sbase[sub] + (int)(lrec[j] >> 7);
            ordrec[pos] = r32[j];
            ordsub[pos] = (unsigned char)sub;
        }
    }
    __syncthreads();
    int mloc = (int)(m - base);
    if (mloc > SP_CHUNK) mloc = SP_CHUNK;
    if (mloc < 0) mloc = 0;
    for (int i = t; i < mloc; i += 256) {
        int sub = ordsub[i];
        int gpos = gbase[sub] + (i - sbase[sub]);
        if (gpos < cap2) buf2[(size_t)(s * 128 + sub) * cap2 + gpos] = ordrec[i];
    }
}

// ---------------- merged: degree+dinv+rowstart + CSR scatter ----------------
__global__ __launch_bounds__(256) void binBC_kernel(const int* __restrict__ cnt2,
                                                    const uint32_t* __restrict__ buf2,
                                                    int* __restrict__ cnt,
                                                    float* __restrict__ dinv,
                                                    int* __restrict__ rowstart,
                                                    int* __restrict__ col,
                                                    int n, int cap2) {
    __shared__ int h[64];
    __shared__ int rowst[64];
    __shared__ int cur[64];
    __shared__ int sc[64];
    int bin = blockIdx.x;
    int t = threadIdx.x;
    if (t < 64) {
        h[t] = (bin * 64 + t < n) ? 1 : 0;  // self-loop pre-counted
        cur[t] = 1;                         // slot 0 reserved for self
    }
    __syncthreads();
    int m = cnt2[bin];
    if (m > cap2) m = cap2;
    const uint32_t* buf = buf2 + (size_t)bin * cap2;
    for (int i = t; i < m; i += 256) atomicAdd(&h[buf[i] & 63], 1);
    __syncthreads();
    int c = 0, pc = 0;
    if (t < 64) { c = h[t]; pc = (c + 7) & ~7; sc[t] = pc; }
    __syncthreads();
    for (int off = 1; off < 64; off <<= 1) {
        int v = 0;
        if (t < 64 && t >= off) v = sc[t - off];
        __syncthreads();
        if (t < 64) sc[t] += v;
        __syncthreads();
    }
    if (t < 64) {
        int node = bin * 64 + t;
        int base = bin * cap2;
        int st = base + sc[t] - pc;
        rowst[t] = st;
        if (node < n) {
            cnt[node] = c;
            dinv[node] = rsqrtf((float)c);
            rowstart[node] = st;
            col[st] = node;                       // self-loop entry
            for (int k = c; k < pc; ++k) col[st + k] = n;  // sentinel pad
        }
    }
    __syncthreads();
    for (int i = t; i < m; i += 256) {
        uint32_t rec = buf[i];
        int d6 = rec & 63;
        int off = atomicAdd(&cur[d6], 1);
        col[rowst[d6] + off] = (int)(rec >> 6);
    }
}

// ---------------- MFMA GEMM + dinv row-scale epilogue; OUT_FP8 packs e4m3 ----------
// Block 0 also zeroes the sentinel row (bytes [n*NCOL, n*NCOL+NCOL)).
template <int NCOL, int A_FP32, int OUT_FP8>
__global__ __launch_bounds__(256) void gemm_mfma(const void* __restrict__ Av,
                                                 const unsigned short* __restrict__ Wf,
                                                 const float* __restrict__ dinv,
                                                 void* __restrict__ Cv, int n) {
    __shared__ unsigned short lds[NCOL * 128];
    const int t = threadIdx.x;
    if (blockIdx.x == 0 && t < NCOL / 4)
        ((uint32_t*)Cv)[(size_t)n * (NCOL / 4) + t] = 0;
    for (int i = t; i < NCOL * 16; i += 256)
        ((uint4*)lds)[i] = ((const uint4*)Wf)[i];
    __syncthreads();

    const int wave = t >> 6, lane = t & 63;
    const int row0 = blockIdx.x * 64 + wave * 16;
    const int m = lane & 15, quad = lane >> 4;
    int arow = row0 + m;
    if (arow >= n) arow = n - 1;

    short8v a[4];
    if (A_FP32) {
        const float* A = (const float*)Av;
#pragma unroll
        for (int ks = 0; ks < 4; ++ks) {
            float4 lo = *(const float4*)(A + (size_t)arow * 128 + ks * 32 + quad * 8);
            float4 hi = *(const float4*)(A + (size_t)arow * 128 + ks * 32 + quad * 8 + 4);
            union { short8v v; uint32_t u[4]; } pk;
            pk.u[0] = f2_to_bf2(lo.x, lo.y);
            pk.u[1] = f2_to_bf2(lo.z, lo.w);
            pk.u[2] = f2_to_bf2(hi.x, hi.y);
            pk.u[3] = f2_to_bf2(hi.z, hi.w);
            a[ks] = pk.v;
        }
    } else {
        const unsigned short* A = (const unsigned short*)Av;
#pragma unroll
        for (int ks = 0; ks < 4; ++ks)
            a[ks] = *(const short8v*)(A + (size_t)arow * 128 + ks * 32 + quad * 8);
    }

    const int cr0 = row0 + quad * 4;
    float ds[4];
#pragma unroll
    for (int r = 0; r < 4; ++r) {
        int gr = cr0 + r;
        ds[r] = (gr < n) ? dinv[gr] : 0.0f;
    }
#pragma unroll
    for (int ct = 0; ct < NCOL / 16; ++ct) {
        float4v acc = {0.0f, 0.0f, 0.0f, 0.0f};
#pragma unroll
        for (int ks = 0; ks < 4; ++ks) {
            int f = ct * 4 + ks;
            short8v b = *(const short8v*)(lds + ((size_t)(f * 64 + lane)) * 8);
            acc = __builtin_amdgcn_mfma_f32_16x16x32_bf16(a[ks], b, acc, 0, 0, 0);
        }
#pragma unroll
        for (int r = 0; r < 4; ++r) {
            int gr = cr0 + r;
            if (gr < n) {
                float val = acc[r] * ds[r];
                if (OUT_FP8) {
                    int u = __builtin_amdgcn_cvt_pk_fp8_f32(val, val, 0, false);
                    ((unsigned char*)Cv)[(size_t)gr * NCOL + ct * 16 + m] =
                        (unsigned char)(u & 0xFF);
                } else {
                    ((unsigned short*)Cv)[(size_t)gr * NCOL + ct * 16 + m] = f_to_bf(val);
                }
            }
        }
    }
}

// ---------------- sliced 2-node aggregation, 128 feats, fp8 T (128B rows) ---------
// Feature-sliced for L2 residency: each block handles ONE 32-byte column slice
// (slice = (blockIdx>>1)&3, tied to XCD via blockIdx%8 round-robin; 2 XCDs per
// slice -> 3.2 MB slice working set fits the 4 MiB per-XCD L2, so T gathers
// become L2 hits instead of misses). col[] is re-read once per slice (cheap
// streaming). Correctness does not depend on the XCD mapping.
// lane bits: j = b0-b1 (4 lanes x 8B = 32B slice), slot = b2-b4 (8 edge slots),
// sel = b5 (node). 4-stage sentinel-masked preload + rare tail (deg > 32).
// Slot reduce: ror4 + ror8 + swz16 (bits 2,3,4).
__global__ __launch_bounds__(256) void agg_relu_128_fp8(
        const uint32_t* __restrict__ T8, const int* __restrict__ rowstart,
        const int* __restrict__ cnt, const int* __restrict__ col,
        const float* __restrict__ dinv, const float* __restrict__ bias,
        uint32_t* __restrict__ outHb, int n) {
    int b = blockIdx.x;
    int slice = (b >> 1) & 3;            // XCD-pinned slice
    int p = (b >> 3) * 2 + (b & 1);      // node-pair-group [0, ceil(n/8))
    int wid = p * 4 + (threadIdx.x >> 6);
    int lane = threadIdx.x & 63;
    int j = lane & 3, slot = (lane >> 2) & 7, sel = lane >> 5;
    int nodeA = wid * 2;
    int node = nodeA + sel;
    if (nodeA >= n) return;
    bool valid = node < n;
    int nd = valid ? node : nodeA;
    int start = rowstart[nd];
    int c = cnt[nd];
    int nit = valid ? (((c + 7) & ~7) >> 3) : 0;   // stages of 8 edges

    float2v acc2[4];
#pragma unroll
    for (int k = 0; k < 4; ++k) acc2[k] = (float2v){0.0f, 0.0f};
    const uint2* T2 = (const uint2*)T8;
    int bp = start + slot;
    int fo = slice * 4 + j;              // uint2 offset within 16-uint2 row
    int a0 = col[bp +  0];
    int a1 = col[bp +  8];
    int a2 = col[bp + 16];
    int a3 = col[bp + 24];
    a0 = (0 < nit) ? a0 : n;
    a1 = (1 < nit) ? a1 : n;
    a2 = (2 < nit) ? a2 : n;
    a3 = (3 < nit) ? a3 : n;
    uint2 v0 = T2[(size_t)a0 * 16 + fo];
    uint2 v1 = T2[(size_t)a1 * 16 + fo];
    uint2 v2 = T2[(size_t)a2 * 16 + fo];
    uint2 v3 = T2[(size_t)a3 * 16 + fo];
    acc8_fp8_pk(acc2, v0);
    acc8_fp8_pk(acc2, v1);
    acc8_fp8_pk(acc2, v2);
    acc8_fp8_pk(acc2, v3);
    for (int s = 4; s < nit; ++s) {
        int aa = col[bp + s * 8];
        uint2 w = T2[(size_t)aa * 16 + fo];
        acc8_fp8_pk(acc2, w);
    }
    float* acc = (float*)acc2;
#pragma unroll
    for (int k = 0; k < 8; ++k) acc[k] += dppmov<0x124>(acc[k]);  // ror4 (bit2)
#pragma unroll
    for (int k = 0; k < 8; ++k) acc[k] += dppmov<0x128>(acc[k]);  // ror8 (bit3)
#pragma unroll
    for (int k = 0; k < 8; ++k) acc[k] += swz16f(acc[k]);         // xor16 (bit4)
    if (slot == 0 && valid) {
        float di = dinv[node];
        const float4* b4 = (const float4*)bias;
        float4 bb0 = b4[slice * 8 + j * 2];
        float4 bb1 = b4[slice * 8 + j * 2 + 1];
        float r[8];
        r[0] = fmaxf(di * acc[0] + bb0.x, 0.0f);
        r[1] = fmaxf(di * acc[1] + bb0.y, 0.0f);
        r[2] = fmaxf(di * acc[2] + bb0.z, 0.0f);
        r[3] = fmaxf(di * acc[3] + bb0.w, 0.0f);
        r[4] = fmaxf(di * acc[4] + bb1.x, 0.0f);
        r[5] = fmaxf(di * acc[5] + bb1.y, 0.0f);
        r[6] = fmaxf(di * acc[6] + bb1.z, 0.0f);
        r[7] = fmaxf(di * acc[7] + bb1.w, 0.0f);
        uint4 o;
        o.x = f2_to_bf2(r[0], r[1]);
        o.y = f2_to_bf2(r[2], r[3]);
        o.z = f2_to_bf2(r[4], r[5]);
        o.w = f2_to_bf2(r[6], r[7]);
        *(uint4*)(outHb + (size_t)node * 64 + slice * 16 + j * 4) = o;
    }
}

// ---------------- 2-node aggregation, 64 feats fp8 (64B rows) + log_softmax --------
// Unsliced: log_softmax needs all 64 features per node. lane bits: j = b0-b1
// (4 chunks x 16B), slot = b2-b4 (8 slots), sel = b5. 4-stage preload + tail.
__global__ __launch_bounds__(256) void agg_lsm_64_fp8(
        const uint32_t* __restrict__ T8, const int* __restrict__ rowstart,
        const int* __restrict__ cnt, const int* __restrict__ col,
        const float* __restrict__ dinv, const float* __restrict__ bias,
        float* __restrict__ out, int n) {
    int wid = blockIdx.x * 4 + (threadIdx.x >> 6);
    int lane = threadIdx.x & 63;
    int j = lane & 3, slot = (lane >> 2) & 7, sel = lane >> 5;
    int nodeA = wid * 2;
    int node = nodeA + sel;
    if (nodeA >= n) return;
    bool valid = node < n;
    int nd = valid ? node : nodeA;
    int start = rowstart[nd];
    int c = cnt[nd];
    int nit = valid ? (((c + 7) & ~7) >> 3) : 0;   // stages of 8 edges

    float2v acc2[8];
#pragma unroll
    for (int k = 0; k < 8; ++k) acc2[k] = (float2v){0.0f, 0.0f};
    const uint4* T4 = (const uint4*)T8;
    int bp = start + slot;
    int a0 = col[bp +  0];
    int a1 = col[bp +  8];
    int a2 = col[bp + 16];
    int a3 = col[bp + 24];
    a0 = (0 < nit) ? a0 : n;
    a1 = (1 < nit) ? a1 : n;
    a2 = (2 < nit) ? a2 : n;
    a3 = (3 < nit) ? a3 : n;
    uint4 v0 = T4[(size_t)a0 * 4 + j];
    uint4 v1 = T4[(size_t)a1 * 4 + j];
    uint4 v2 = T4[(size_t)a2 * 4 + j];
    uint4 v3 = T4[(size_t)a3 * 4 + j];
    acc16_fp8_pk(acc2, v0);
    acc16_fp8_pk(acc2, v1);
    acc16_fp8_pk(acc2, v2);
    acc16_fp8_pk(acc2, v3);
    for (int s = 4; s < nit; ++s) {
        int aa = col[bp + s * 8];
        uint4 w = T4[(size_t)aa * 4 + j];
        acc16_fp8_pk(acc2, w);
    }
    float* acc = (float*)acc2;
#pragma unroll
    for (int k = 0; k < 16; ++k) acc[k] += dppmov<0x124>(acc[k]);  // ror4 (bit2)
#pragma unroll
    for (int k = 0; k < 16; ++k) acc[k] += dppmov<0x128>(acc[k]);  // ror8 (bit3)
#pragma unroll
    for (int k = 0; k < 16; ++k) acc[k] += swz16f(acc[k]);         // xor16 (bit4)
    float di = dinv[nd];
    const float4* b4 = (const float4*)bias;
    float r[16];
#pragma unroll
    for (int q = 0; q < 4; ++q) {
        float4 bb = b4[j * 4 + q];
        r[q * 4 + 0] = di * acc[q * 4 + 0] + bb.x;
        r[q * 4 + 1] = di * acc[q * 4 + 1] + bb.y;
        r[q * 4 + 2] = di * acc[q * 4 + 2] + bb.z;
        r[q * 4 + 3] = di * acc[q * 4 + 3] + bb.w;
    }
    // log_softmax over 64 feats: 16 local + j-reduce over lane bits 0,1
    float m0 = fmaxf(fmaxf(r[0], r[1]), fmaxf(r[2], r[3]));
    float m1 = fmaxf(fmaxf(r[4], r[5]), fmaxf(r[6], r[7]));
    float m2 = fmaxf(fmaxf(r[8], r[9]), fmaxf(r[10], r[11]));
    float m3 = fmaxf(fmaxf(r[12], r[13]), fmaxf(r[14], r[15]));
    float m = fmaxf(fmaxf(m0, m1), fmaxf(m2, m3));
    m = fmaxf(m, dppmov<0xB1>(m));   // xor1
    m = fmaxf(m, dppmov<0x4E>(m));   // xor2
    float e0 = __expf(r[0] - m) + __expf(r[1] - m) + __expf(r[2] - m) +
               __expf(r[3] - m);
    float e1 = __expf(r[4] - m) + __expf(r[5] - m) + __expf(r[6] - m) +
               __expf(r[7] - m);
    float e2 = __expf(r[8] - m) + __expf(r[9] - m) + __expf(r[10] - m) +
               __expf(r[11] - m);
    float e3 = __expf(r[12] - m) + __expf(r[13] - m) + __expf(r[14] - m) +
               __expf(r[15] - m);
    float ss = (e0 + e1) + (e2 + e3);
    ss += dppmov<0xB1>(ss);
    ss += dppmov<0x4E>(ss);
    float lg = m + __logf(ss);
    if (slot == 0 && valid) {
#pragma unroll
        for (int q = 0; q < 4; ++q) {
            float4 o = make_float4(r[q * 4 + 0] - lg, r[q * 4 + 1] - lg,
                                   r[q * 4 + 2] - lg, r[q * 4 + 3] - lg);
            *(float4*)(out + (size_t)node * 64 + j * 16 + q * 4) = o;
        }
    }
}

// ---------------- launcher ----------------
extern "C" void kernel_launch(void* const* d_in, const int* in_sizes, int n_in,
                              void* d_out, int out_size, void* d_ws, size_t ws_size,
                              hipStream_t stream) {
    const float* x  = (const float*)d_in[0];
    const void*  ei = d_in[1];
    const float* W1 = (const float*)d_in[2];
    const float* b1 = (const float*)d_in[3];
    const float* W2 = (const float*)d_in[4];
    const float* b2 = (const float*)d_in[5];
    const float* W3 = (const float*)d_in[6];
    const float* b3 = (const float*)d_in[7];
    float* out = (float*)d_out;

    const int n = in_sizes[0] / FIN;       // 100000
    const int E = in_sizes[1] / 2;         // 1600000

    char* p = (char*)d_ws;
    auto carve = [&](size_t bytes) {
        char* q = p;
        p += (bytes + 255) & ~(size_t)255;
        return q;
    };
    const int NB = (n + 63) / 64;
    const int NS = (n + 8191) / 8192;

    long long meanS = (long long)E * 8192 / n;
    int capS = (int)(meanS + 8 * (long long)sqrt((double)meanS) + 1024);
    capS = (capS + 15) & ~15;
    long long mean2 = (long long)E * 64 / n;
    // + self-loops (64) + per-node x8 padding (<=448) + tail slack
    int cap2 = (int)(mean2 + 8 * (long long)sqrt((double)mean2) + 1152);
    cap2 = (cap2 + 15) & ~15;

    int*   cnt      = (int*)carve((size_t)n * 4);
    int*   rowstart = (int*)carve((size_t)n * 4);
    float* dinv     = (float*)carve((size_t)n * 4);
    int*   colb     = (int*)carve(((size_t)NB * cap2 + 4096) * 4);
    int*   gCnt     = (int*)carve((size_t)(16 + NB) * 4);
    int*   cnt2     = gCnt + 16;
    // T: fp8 n*128 + 256B sentinel zero-row; Hb bf16 n*128.
    size_t Tbytes = (size_t)n * 128 + 256;
    size_t Hbytes = (size_t)n * 128 * 2;
    char*  TH = carve(Tbytes + Hbytes);
    void*  T  = (void*)TH;
    unsigned short* Hb = (unsigned short*)(TH + Tbytes);
    unsigned short* Wf1 = (unsigned short*)carve(128 * 128 * 2);
    unsigned short* Wf2 = (unsigned short*)carve(128 * 128 * 2);
    unsigned short* Wf3 = (unsigned short*)carve(128 * 64 * 2);

    // split bufs alias the T+Hb region (free during preprocessing)
    size_t buf1B = ((size_t)NS * capS * 4 + 255) & ~(size_t)255;
    uint32_t* buf1 = (uint32_t*)TH;
    uint32_t* buf2 = (uint32_t*)(TH + buf1B);
    size_t avail2 = (Tbytes + Hbytes > buf1B) ? (Tbytes + Hbytes - buf1B) : 0;
    size_t maxc2 = avail2 / ((size_t)NB * 4);
    if ((size_t)cap2 > maxc2) cap2 = (int)maxc2;

    hipMemsetAsync(gCnt, 0, (size_t)(16 + NB) * 4, stream);

    const int gagg2 = ((n + 1) / 2 + 3) / 4;              // node-pair groups
    const int gaggS = ((gagg2 + 1) / 2) * 8;              // sliced relu grid
    const int ggemm = (n + 63) / 64;
    const int gsplitA = (E + SP_CHUNK - 1) / SP_CHUNK;
    const int gsplitBx = (capS + SP_CHUNK - 1) / SP_CHUNK;

    splitA_kernel<<<gsplitA + 20, 256, 0, stream>>>(ei, gCnt, buf1, E, capS, gsplitA,
                                                    W1, W2, W3, Wf1, Wf2, Wf3);
    splitB_kernel<<<dim3(gsplitBx, NS), 256, 0, stream>>>(gCnt, buf1, cnt2, buf2, capS,
                                                          cap2, NB);
    binBC_kernel<<<NB, 256, 0, stream>>>(cnt2, buf2, cnt, dinv, rowstart, colb, n,
                                         cap2);

    // layer 1: T(fp8) = dinv * (x @ W1) ; Hb(bf16) = relu(di*(sum T) + b1)
    gemm_mfma<128, 1, 1><<<ggemm, 256, 0, stream>>>(x, Wf1, dinv, T, n);
    agg_relu_128_fp8<<<gaggS, 256, 0, stream>>>((const uint32_t*)T, rowstart, cnt,
                                                colb, dinv, b1, (uint32_t*)Hb, n);
    // layer 2
    gemm_mfma<128, 0, 1><<<ggemm, 256, 0, stream>>>(Hb, Wf2, dinv, T, n);
    agg_relu_128_fp8<<<gaggS, 256, 0, stream>>>((const uint32_t*)T, rowstart, cnt,
                                                colb, dinv, b2, (uint32_t*)Hb, n);
    // layer 3: T(fp8, 64 cols) = dinv * (Hb @ W3) ; out = log_softmax(...)
    gemm_mfma<64, 0, 1><<<ggemm, 256, 0, stream>>>(Hb, Wf3, dinv, T, n);
    agg_lsm_64_fp8<<<gagg2, 256, 0, stream>>>((const uint32_t*)T, rowstart, cnt, colb,
                                              dinv, b3, out, n);
}

// Round 8
// 295.483 us; speedup vs baseline: 1.3864x; 1.3864x over previous
//
#include <hip/hip_runtime.h>
#include <stdint.h>
#include <math.h>

#define FIN 128

typedef __attribute__((ext_vector_type(8))) short short8v;
typedef __attribute__((ext_vector_type(4))) float float4v;
typedef __attribute__((ext_vector_type(2))) float float2v;

// ---------------- bf16 helpers ----------------
__device__ __forceinline__ uint32_t f2_to_bf2(float x, float y) {
    uint32_t r;
    asm("v_cvt_pk_bf16_f32 %0, %1, %2" : "=v"(r) : "v"(x), "v"(y));
    return r;
}
__device__ __forceinline__ unsigned short f_to_bf(float x) {
    union { float f; uint32_t i; } a;
    a.f = x;
    uint32_t u = a.i + 0x7FFF + ((a.i >> 16) & 1);
    return (unsigned short)(u >> 16);
}
// acc2[0..7] (+)= 16 fp8 decoded (packed adds)
__device__ __forceinline__ void acc16_fp8_pk(float2v* acc2, uint4 v) {
    uint32_t us[4] = {v.x, v.y, v.z, v.w};
#pragma unroll
    for (int q = 0; q < 4; ++q) {
        acc2[q * 2 + 0] += __builtin_amdgcn_cvt_pk_f32_fp8(us[q], false);
        acc2[q * 2 + 1] += __builtin_amdgcn_cvt_pk_f32_fp8(us[q], true);
    }
}

// DPP cross-lane move on the VALU pipe: quad_perm / row_ror.
// xor1 = quad_perm[1,0,3,2] = 0xB1 ; xor2 = quad_perm[2,3,0,1] = 0x4E
// ror4 = 0x124 ; ror8 = 0x128. Rotation-sum within the 16-lane ring is a
// valid all-lanes reduce over the rotated bit(s).
template <int CTRL>
__device__ __forceinline__ float dppmov(float x) {
    int i = __builtin_bit_cast(int, x);
    int r = __builtin_amdgcn_update_dpp(i, i, CTRL, 0xF, 0xF, false);
    return __builtin_bit_cast(float, r);
}
__device__ __forceinline__ float swz16f(float x) {
    int r = __builtin_amdgcn_ds_swizzle(__builtin_bit_cast(int, x), 0x401F);
    return __builtin_bit_cast(float, r);
}

__device__ __forceinline__ int edge_at(const void* ei, long long idx, int is32) {
    return is32 ? ((const int*)ei)[idx] : (int)((const long long*)ei)[idx];
}

// ---------------- Level-1 split (16 super-bins, dst>>13) + fused W-conv ----------
// record = (src<<13)|(dst&8191), 30 bits (requires n < 2^19; here n = 100000)
// Blocks [nA, nA+20) run the weight->fragment-ordered bf16 conversion instead.
#define SP_CHUNK 4096
__global__ __launch_bounds__(256) void splitA_kernel(
        const void* __restrict__ ei, int* __restrict__ gCnt,
        uint32_t* __restrict__ buf1, int E, int capS, int nA,
        const float* __restrict__ W1, const float* __restrict__ W2,
        const float* __restrict__ W3, unsigned short* __restrict__ Wf1,
        unsigned short* __restrict__ Wf2, unsigned short* __restrict__ Wf3) {
    __shared__ int hist[16];
    __shared__ int gbase[16];
    __shared__ int lflag;
    int t = threadIdx.x;
    if (blockIdx.x >= nA) {
        // ---- fused wconv ----
        int idx = (blockIdx.x - nA) * 256 + t;
        const float* W;
        unsigned short* Wf;
        int NCOL, base;
        if (idx < 2048)      { W = W1; Wf = Wf1; NCOL = 128; base = idx; }
        else if (idx < 4096) { W = W2; Wf = Wf2; NCOL = 128; base = idx - 2048; }
        else if (idx < 5120) { W = W3; Wf = Wf3; NCOL = 64;  base = idx - 4096; }
        else return;
        int f = base >> 6, l = base & 63;
        int ct = f >> 2, ks = f & 3;
        int nn = ct * 16 + (l & 15);
        int k0 = ks * 32 + (l >> 4) * 8;
        uint32_t pk[4];
#pragma unroll
        for (int j = 0; j < 4; ++j) {
            float a = W[(size_t)(k0 + 2 * j) * NCOL + nn];
            float b = W[(size_t)(k0 + 2 * j + 1) * NCOL + nn];
            pk[j] = f2_to_bf2(a, b);
        }
        ((uint4*)Wf)[base] = make_uint4(pk[0], pk[1], pk[2], pk[3]);
        return;
    }
    if (t < 16) hist[t] = 0;
    if (t == 0) lflag = 0;
    long long base = (long long)blockIdx.x * SP_CHUNK;
    __syncthreads();
    {
        long long e = base + t;
        if (e < E && ((const int*)ei)[2 * e + 1] != 0) atomicOr(&lflag, 1);
    }
    __syncthreads();
    int is32 = lflag;
    uint32_t lrec[16], rec[16];
#pragma unroll
    for (int j = 0; j < 16; ++j) {
        long long e = base + t + j * 256;
        if (e < E) {
            int s = edge_at(ei, e, is32);
            int d = edge_at(ei, (long long)E + e, is32);
            int b = d >> 13;
            int lofs = atomicAdd(&hist[b], 1);
            lrec[j] = ((uint32_t)lofs << 4) | (uint32_t)b;
            rec[j] = ((uint32_t)s << 13) | (uint32_t)(d & 8191);
        } else
            lrec[j] = 0xFFFFFFFFu;
    }
    __syncthreads();
    if (t < 16) gbase[t] = atomicAdd(&gCnt[t], hist[t]);
    __syncthreads();
#pragma unroll
    for (int j = 0; j < 16; ++j) {
        if (lrec[j] != 0xFFFFFFFFu) {
            int b = lrec[j] & 15;
            int pos = gbase[b] + (int)(lrec[j] >> 4);
            if (pos < capS) buf1[(size_t)b * capS + pos] = rec[j];
        }
    }
}

// ---------------- Level-2 split: 128 sub-bins, LDS counting sort ----------------
__global__ __launch_bounds__(256) void splitB_kernel(const int* __restrict__ gCnt,
                                                     const uint32_t* __restrict__ buf1,
                                                     int* __restrict__ cnt2,
                                                     uint32_t* __restrict__ buf2,
                                                     int capS, int cap2, int NB) {
    __shared__ int hist[128];
    __shared__ int sbase[128];
    __shared__ int gbase[128];
    __shared__ uint32_t ordrec[SP_CHUNK];
    __shared__ unsigned char ordsub[SP_CHUNK];
    int t = threadIdx.x;
    int s = blockIdx.y;
    if (t < 128) hist[t] = 0;
    __syncthreads();
    int m = gCnt[s];
    if (m > capS) m = capS;
    long long base = (long long)blockIdx.x * SP_CHUNK;
    uint32_t lrec[16], r32[16];
#pragma unroll
    for (int j = 0; j < 16; ++j) {
        long long i = base + t + j * 256;
        if (i < m) {
            uint32_t r = buf1[(size_t)s * capS + i];
            int d13 = (int)(r & 8191u);
            int sub = d13 >> 6;
            int lofs = atomicAdd(&hist[sub], 1);
            lrec[j] = ((uint32_t)lofs << 7) | (uint32_t)sub;
            r32[j] = ((r >> 13) << 6) | (uint32_t)(d13 & 63);
        } else
            lrec[j] = 0xFFFFFFFFu;
    }
    __syncthreads();
    if (t < 128) sbase[t] = hist[t];
    __syncthreads();
    for (int off = 1; off < 128; off <<= 1) {
        int v = 0;
        if (t < 128 && t >= off) v = sbase[t - off];
        __syncthreads();
        if (t < 128) sbase[t] += v;
        __syncthreads();
    }
    if (t < 128) {
        int g = s * 128 + t;
        gbase[t] = (g < NB && hist[t] > 0) ? atomicAdd(&cnt2[g], hist[t]) : 0;
        sbase[t] -= hist[t];  // exclusive scan
    }
    __syncthreads();
#pragma unroll
    for (int j = 0; j < 16; ++j) {
        if (lrec[j] != 0xFFFFFFFFu) {
            int sub = lrec[j] & 127;
            int pos = sbase[sub] + (int)(lrec[j] >> 7);
            ordrec[pos] = r32[j];
            ordsub[pos] = (unsigned char)sub;
        }
    }
    __syncthreads();
    int mloc = (int)(m - base);
    if (mloc > SP_CHUNK) mloc = SP_CHUNK;
    if (mloc < 0) mloc = 0;
    for (int i = t; i < mloc; i += 256) {
        int sub = ordsub[i];
        int gpos = gbase[sub] + (i - sbase[sub]);
        if (gpos < cap2) buf2[(size_t)(s * 128 + sub) * cap2 + gpos] = ordrec[i];
    }
}

// ---------------- merged: degree+dinv+rowstart + CSR scatter ----------------
__global__ __launch_bounds__(256) void binBC_kernel(const int* __restrict__ cnt2,
                                                    const uint32_t* __restrict__ buf2,
                                                    int* __restrict__ cnt,
                                                    float* __restrict__ dinv,
                                                    int* __restrict__ rowstart,
                                                    int* __restrict__ col,
                                                    int n, int cap2) {
    __shared__ int h[64];
    __shared__ int rowst[64];
    __shared__ int cur[64];
    __shared__ int sc[64];
    int bin = blockIdx.x;
    int t = threadIdx.x;
    if (t < 64) {
        h[t] = (bin * 64 + t < n) ? 1 : 0;  // self-loop pre-counted
        cur[t] = 1;                         // slot 0 reserved for self
    }
    __syncthreads();
    int m = cnt2[bin];
    if (m > cap2) m = cap2;
    const uint32_t* buf = buf2 + (size_t)bin * cap2;
    for (int i = t; i < m; i += 256) atomicAdd(&h[buf[i] & 63], 1);
    __syncthreads();
    int c = 0, pc = 0;
    if (t < 64) { c = h[t]; pc = (c + 7) & ~7; sc[t] = pc; }
    __syncthreads();
    for (int off = 1; off < 64; off <<= 1) {
        int v = 0;
        if (t < 64 && t >= off) v = sc[t - off];
        __syncthreads();
        if (t < 64) sc[t] += v;
        __syncthreads();
    }
    if (t < 64) {
        int node = bin * 64 + t;
        int base = bin * cap2;
        int st = base + sc[t] - pc;
        rowst[t] = st;
        if (node < n) {
            cnt[node] = c;
            dinv[node] = rsqrtf((float)c);
            rowstart[node] = st;
            col[st] = node;                       // self-loop entry
            for (int k = c; k < pc; ++k) col[st + k] = n;  // sentinel pad
        }
    }
    __syncthreads();
    for (int i = t; i < m; i += 256) {
        uint32_t rec = buf[i];
        int d6 = rec & 63;
        int off = atomicAdd(&cur[d6], 1);
        col[rowst[d6] + off] = (int)(rec >> 6);
    }
}

// ---------------- MFMA GEMM + dinv row-scale epilogue; OUT_FP8 packs e4m3 ----------
// Block 0 also zeroes the sentinel row (bytes [n*NCOL, n*NCOL+NCOL)).
template <int NCOL, int A_FP32, int OUT_FP8>
__global__ __launch_bounds__(256) void gemm_mfma(const void* __restrict__ Av,
                                                 const unsigned short* __restrict__ Wf,
                                                 const float* __restrict__ dinv,
                                                 void* __restrict__ Cv, int n) {
    __shared__ unsigned short lds[NCOL * 128];
    const int t = threadIdx.x;
    if (blockIdx.x == 0 && t < NCOL / 4)
        ((uint32_t*)Cv)[(size_t)n * (NCOL / 4) + t] = 0;
    for (int i = t; i < NCOL * 16; i += 256)
        ((uint4*)lds)[i] = ((const uint4*)Wf)[i];
    __syncthreads();

    const int wave = t >> 6, lane = t & 63;
    const int row0 = blockIdx.x * 64 + wave * 16;
    const int m = lane & 15, quad = lane >> 4;
    int arow = row0 + m;
    if (arow >= n) arow = n - 1;

    short8v a[4];
    if (A_FP32) {
        const float* A = (const float*)Av;
#pragma unroll
        for (int ks = 0; ks < 4; ++ks) {
            float4 lo = *(const float4*)(A + (size_t)arow * 128 + ks * 32 + quad * 8);
            float4 hi = *(const float4*)(A + (size_t)arow * 128 + ks * 32 + quad * 8 + 4);
            union { short8v v; uint32_t u[4]; } pk;
            pk.u[0] = f2_to_bf2(lo.x, lo.y);
            pk.u[1] = f2_to_bf2(lo.z, lo.w);
            pk.u[2] = f2_to_bf2(hi.x, hi.y);
            pk.u[3] = f2_to_bf2(hi.z, hi.w);
            a[ks] = pk.v;
        }
    } else {
        const unsigned short* A = (const unsigned short*)Av;
#pragma unroll
        for (int ks = 0; ks < 4; ++ks)
            a[ks] = *(const short8v*)(A + (size_t)arow * 128 + ks * 32 + quad * 8);
    }

    const int cr0 = row0 + quad * 4;
    float ds[4];
#pragma unroll
    for (int r = 0; r < 4; ++r) {
        int gr = cr0 + r;
        ds[r] = (gr < n) ? dinv[gr] : 0.0f;
    }
#pragma unroll
    for (int ct = 0; ct < NCOL / 16; ++ct) {
        float4v acc = {0.0f, 0.0f, 0.0f, 0.0f};
#pragma unroll
        for (int ks = 0; ks < 4; ++ks) {
            int f = ct * 4 + ks;
            short8v b = *(const short8v*)(lds + ((size_t)(f * 64 + lane)) * 8);
            acc = __builtin_amdgcn_mfma_f32_16x16x32_bf16(a[ks], b, acc, 0, 0, 0);
        }
#pragma unroll
        for (int r = 0; r < 4; ++r) {
            int gr = cr0 + r;
            if (gr < n) {
                float val = acc[r] * ds[r];
                if (OUT_FP8) {
                    int u = __builtin_amdgcn_cvt_pk_fp8_f32(val, val, 0, false);
                    ((unsigned char*)Cv)[(size_t)gr * NCOL + ct * 16 + m] =
                        (unsigned char)(u & 0xFF);
                } else {
                    ((unsigned short*)Cv)[(size_t)gr * NCOL + ct * 16 + m] = f_to_bf(val);
                }
            }
        }
    }
}

// ---------------- 2-node aggregation, 128 feats, fp8 T (128B rows) ----------------
// REVERTED to the unsliced round-5 form (slicing quadrupled line-granular
// fetch traffic). lane bits: j = b0-b2 (8 chunks x 16B, contiguous 128B rows),
// slot = b3-b4 (4 edge slots), sel = b5 (node).
// Wave-uniform early-out: stages 0-1 always (deg <= 16); stages 2-3 + tail
// only if degM > 2 (degM = max nit over the wave's 2 nodes). ~33% of waves
// skip half the gather+decode. All gathers issue before any decode.
// Slot reduce: row_ror:8 (bit3) + ds_swizzle xor16 (bit4).
__global__ __launch_bounds__(256) void agg_relu_128_fp8(
        const uint32_t* __restrict__ T8, const int* __restrict__ rowstart,
        const int* __restrict__ cnt, const int* __restrict__ col,
        const float* __restrict__ dinv, const float* __restrict__ bias,
        uint32_t* __restrict__ outHb, int n) {
    int wid = blockIdx.x * 4 + (threadIdx.x >> 6);
    int lane = threadIdx.x & 63;
    int j = lane & 7, slot = (lane >> 3) & 3, sel = lane >> 5;
    int nodeA = wid * 2;
    int node = nodeA + sel;
    if (nodeA >= n) return;
    bool valid = node < n;
    int nd = valid ? node : nodeA;
    int start = rowstart[nd];
    int c = cnt[nd];
    int nit = valid ? (((c + 7) & ~7) >> 3) : 0;   // stages of 8 edges
    int degM = max(nit, __shfl_xor(nit, 32, 64));  // wave-uniform stage count

    float2v acc2[8];
#pragma unroll
    for (int k = 0; k < 8; ++k) acc2[k] = (float2v){0.0f, 0.0f};
    const uint4* T4 = (const uint4*)T8;
    int bp = start + slot;
    // ---- stages 0-1 (always; every node has >= 1 stage via self-loop) ----
    int s00 = col[bp +  0], s01 = col[bp +  4];
    int s10 = col[bp +  8], s11 = col[bp + 12];
    s00 = (0 < nit) ? s00 : n;  s01 = (0 < nit) ? s01 : n;
    s10 = (1 < nit) ? s10 : n;  s11 = (1 < nit) ? s11 : n;
    uint4 v00 = T4[(size_t)s00 * 8 + j], v01 = T4[(size_t)s01 * 8 + j];
    uint4 v10 = T4[(size_t)s10 * 8 + j], v11 = T4[(size_t)s11 * 8 + j];
    if (degM > 2) {
        // ---- stages 2-3: issue gathers before decoding stages 0-1 ----
        int s20 = col[bp + 16], s21 = col[bp + 20];
        int s30 = col[bp + 24], s31 = col[bp + 28];
        s20 = (2 < nit) ? s20 : n;  s21 = (2 < nit) ? s21 : n;
        s30 = (3 < nit) ? s30 : n;  s31 = (3 < nit) ? s31 : n;
        uint4 v20 = T4[(size_t)s20 * 8 + j], v21 = T4[(size_t)s21 * 8 + j];
        uint4 v30 = T4[(size_t)s30 * 8 + j], v31 = T4[(size_t)s31 * 8 + j];
        acc16_fp8_pk(acc2, v00); acc16_fp8_pk(acc2, v01);
        acc16_fp8_pk(acc2, v10); acc16_fp8_pk(acc2, v11);
        acc16_fp8_pk(acc2, v20); acc16_fp8_pk(acc2, v21);
        acc16_fp8_pk(acc2, v30); acc16_fp8_pk(acc2, v31);
        // ---- rare tail (deg > 32) ----
        for (int s = 4; s < nit; ++s) {
            int a0 = col[bp + s * 8], a1 = col[bp + s * 8 + 4];
            uint4 w0 = T4[(size_t)a0 * 8 + j];
            uint4 w1 = T4[(size_t)a1 * 8 + j];
            acc16_fp8_pk(acc2, w0);
            acc16_fp8_pk(acc2, w1);
        }
    } else {
        acc16_fp8_pk(acc2, v00); acc16_fp8_pk(acc2, v01);
        acc16_fp8_pk(acc2, v10); acc16_fp8_pk(acc2, v11);
    }
    float* acc = (float*)acc2;
#pragma unroll
    for (int k = 0; k < 16; ++k) acc[k] += dppmov<0x128>(acc[k]);  // ror8 (bit3)
#pragma unroll
    for (int k = 0; k < 16; ++k) acc[k] += swz16f(acc[k]);         // xor16 (bit4)
    if (slot == 0 && valid) {
        float di = dinv[node];
        const float4* b4 = (const float4*)bias;
        float r[16];
#pragma unroll
        for (int q = 0; q < 4; ++q) {
            float4 bb = b4[j * 4 + q];
            r[q * 4 + 0] = fmaxf(di * acc[q * 4 + 0] + bb.x, 0.0f);
            r[q * 4 + 1] = fmaxf(di * acc[q * 4 + 1] + bb.y, 0.0f);
            r[q * 4 + 2] = fmaxf(di * acc[q * 4 + 2] + bb.z, 0.0f);
            r[q * 4 + 3] = fmaxf(di * acc[q * 4 + 3] + bb.w, 0.0f);
        }
        uint4 o0, o1;
        o0.x = f2_to_bf2(r[0], r[1]);   o0.y = f2_to_bf2(r[2], r[3]);
        o0.z = f2_to_bf2(r[4], r[5]);   o0.w = f2_to_bf2(r[6], r[7]);
        o1.x = f2_to_bf2(r[8], r[9]);   o1.y = f2_to_bf2(r[10], r[11]);
        o1.z = f2_to_bf2(r[12], r[13]); o1.w = f2_to_bf2(r[14], r[15]);
        *(uint4*)(outHb + (size_t)node * 64 + j * 8) = o0;
        *(uint4*)(outHb + (size_t)node * 64 + j * 8 + 4) = o1;
    }
}

// ---------------- 2-node aggregation, 64 feats fp8 (64B rows) + log_softmax --------
// lane bits: j = b0-b1 (4 chunks x 16B, contiguous 64B rows), slot = b2-b4
// (8 edge slots), sel = b5. Stages 0-1 always; 2-3 + tail only if degM > 2.
// Slot reduce: ror4 + ror8 (bits 2,3) + swz16 (bit 4); softmax j-reduce:
// quad_perm xor1 + xor2 (bits 0,1).
__global__ __launch_bounds__(256) void agg_lsm_64_fp8(
        const uint32_t* __restrict__ T8, const int* __restrict__ rowstart,
        const int* __restrict__ cnt, const int* __restrict__ col,
        const float* __restrict__ dinv, const float* __restrict__ bias,
        float* __restrict__ out, int n) {
    int wid = blockIdx.x * 4 + (threadIdx.x >> 6);
    int lane = threadIdx.x & 63;
    int j = lane & 3, slot = (lane >> 2) & 7, sel = lane >> 5;
    int nodeA = wid * 2;
    int node = nodeA + sel;
    if (nodeA >= n) return;
    bool valid = node < n;
    int nd = valid ? node : nodeA;
    int start = rowstart[nd];
    int c = cnt[nd];
    int nit = valid ? (((c + 7) & ~7) >> 3) : 0;   // stages of 8 edges
    int degM = max(nit, __shfl_xor(nit, 32, 64));

    float2v acc2[8];
#pragma unroll
    for (int k = 0; k < 8; ++k) acc2[k] = (float2v){0.0f, 0.0f};
    const uint4* T4 = (const uint4*)T8;
    int bp = start + slot;
    int a0 = col[bp +  0];
    int a1 = col[bp +  8];
    a0 = (0 < nit) ? a0 : n;
    a1 = (1 < nit) ? a1 : n;
    uint4 v0 = T4[(size_t)a0 * 4 + j];
    uint4 v1 = T4[(size_t)a1 * 4 + j];
    if (degM > 2) {
        int a2 = col[bp + 16];
        int a3 = col[bp + 24];
        a2 = (2 < nit) ? a2 : n;
        a3 = (3 < nit) ? a3 : n;
        uint4 v2 = T4[(size_t)a2 * 4 + j];
        uint4 v3 = T4[(size_t)a3 * 4 + j];
        acc16_fp8_pk(acc2, v0);
        acc16_fp8_pk(acc2, v1);
        acc16_fp8_pk(acc2, v2);
        acc16_fp8_pk(acc2, v3);
        for (int s = 4; s < nit; ++s) {
            int aa = col[bp + s * 8];
            uint4 w = T4[(size_t)aa * 4 + j];
            acc16_fp8_pk(acc2, w);
        }
    } else {
        acc16_fp8_pk(acc2, v0);
        acc16_fp8_pk(acc2, v1);
    }
    float* acc = (float*)acc2;
#pragma unroll
    for (int k = 0; k < 16; ++k) acc[k] += dppmov<0x124>(acc[k]);  // ror4 (bit2)
#pragma unroll
    for (int k = 0; k < 16; ++k) acc[k] += dppmov<0x128>(acc[k]);  // ror8 (bit3)
#pragma unroll
    for (int k = 0; k < 16; ++k) acc[k] += swz16f(acc[k]);         // xor16 (bit4)
    float di = dinv[nd];
    const float4* b4 = (const float4*)bias;
    float r[16];
#pragma unroll
    for (int q = 0; q < 4; ++q) {
        float4 bb = b4[j * 4 + q];
        r[q * 4 + 0] = di * acc[q * 4 + 0] + bb.x;
        r[q * 4 + 1] = di * acc[q * 4 + 1] + bb.y;
        r[q * 4 + 2] = di * acc[q * 4 + 2] + bb.z;
        r[q * 4 + 3] = di * acc[q * 4 + 3] + bb.w;
    }
    // log_softmax over 64 feats: 16 local + j-reduce over lane bits 0,1
    float m0 = fmaxf(fmaxf(r[0], r[1]), fmaxf(r[2], r[3]));
    float m1 = fmaxf(fmaxf(r[4], r[5]), fmaxf(r[6], r[7]));
    float m2 = fmaxf(fmaxf(r[8], r[9]), fmaxf(r[10], r[11]));
    float m3 = fmaxf(fmaxf(r[12], r[13]), fmaxf(r[14], r[15]));
    float m = fmaxf(fmaxf(m0, m1), fmaxf(m2, m3));
    m = fmaxf(m, dppmov<0xB1>(m));   // xor1
    m = fmaxf(m, dppmov<0x4E>(m));   // xor2
    float e0 = __expf(r[0] - m) + __expf(r[1] - m) + __expf(r[2] - m) +
               __expf(r[3] - m);
    float e1 = __expf(r[4] - m) + __expf(r[5] - m) + __expf(r[6] - m) +
               __expf(r[7] - m);
    float e2 = __expf(r[8] - m) + __expf(r[9] - m) + __expf(r[10] - m) +
               __expf(r[11] - m);
    float e3 = __expf(r[12] - m) + __expf(r[13] - m) + __expf(r[14] - m) +
               __expf(r[15] - m);
    float ss = (e0 + e1) + (e2 + e3);
    ss += dppmov<0xB1>(ss);
    ss += dppmov<0x4E>(ss);
    float lg = m + __logf(ss);
    if (slot == 0 && valid) {
#pragma unroll
        for (int q = 0; q < 4; ++q) {
            float4 o = make_float4(r[q * 4 + 0] - lg, r[q * 4 + 1] - lg,
                                   r[q * 4 + 2] - lg, r[q * 4 + 3] - lg);
            *(float4*)(out + (size_t)node * 64 + j * 16 + q * 4) = o;
        }
    }
}

// ---------------- launcher ----------------
extern "C" void kernel_launch(void* const* d_in, const int* in_sizes, int n_in,
                              void* d_out, int out_size, void* d_ws, size_t ws_size,
                              hipStream_t stream) {
    const float* x  = (const float*)d_in[0];
    const void*  ei = d_in[1];
    const float* W1 = (const float*)d_in[2];
    const float* b1 = (const float*)d_in[3];
    const float* W2 = (const float*)d_in[4];
    const float* b2 = (const float*)d_in[5];
    const float* W3 = (const float*)d_in[6];
    const float* b3 = (const float*)d_in[7];
    float* out = (float*)d_out;

    const int n = in_sizes[0] / FIN;       // 100000
    const int E = in_sizes[1] / 2;         // 1600000

    char* p = (char*)d_ws;
    auto carve = [&](size_t bytes) {
        char* q = p;
        p += (bytes + 255) & ~(size_t)255;
        return q;
    };
    const int NB = (n + 63) / 64;
    const int NS = (n + 8191) / 8192;

    long long meanS = (long long)E * 8192 / n;
    int capS = (int)(meanS + 8 * (long long)sqrt((double)meanS) + 1024);
    capS = (capS + 15) & ~15;
    long long mean2 = (long long)E * 64 / n;
    // + self-loops (64) + per-node x8 padding (<=448) + tail slack
    int cap2 = (int)(mean2 + 8 * (long long)sqrt((double)mean2) + 1152);
    cap2 = (cap2 + 15) & ~15;

    int*   cnt      = (int*)carve((size_t)n * 4);
    int*   rowstart = (int*)carve((size_t)n * 4);
    float* dinv     = (float*)carve((size_t)n * 4);
    int*   colb     = (int*)carve(((size_t)NB * cap2 + 4096) * 4);
    int*   gCnt     = (int*)carve((size_t)(16 + NB) * 4);
    int*   cnt2     = gCnt + 16;
    // T: fp8 n*128 + 256B sentinel zero-row; Hb bf16 n*128.
    size_t Tbytes = (size_t)n * 128 + 256;
    size_t Hbytes = (size_t)n * 128 * 2;
    char*  TH = carve(Tbytes + Hbytes);
    void*  T  = (void*)TH;
    unsigned short* Hb = (unsigned short*)(TH + Tbytes);
    unsigned short* Wf1 = (unsigned short*)carve(128 * 128 * 2);
    unsigned short* Wf2 = (unsigned short*)carve(128 * 128 * 2);
    unsigned short* Wf3 = (unsigned short*)carve(128 * 64 * 2);

    // split bufs alias the T+Hb region (free during preprocessing)
    size_t buf1B = ((size_t)NS * capS * 4 + 255) & ~(size_t)255;
    uint32_t* buf1 = (uint32_t*)TH;
    uint32_t* buf2 = (uint32_t*)(TH + buf1B);
    size_t avail2 = (Tbytes + Hbytes > buf1B) ? (Tbytes + Hbytes - buf1B) : 0;
    size_t maxc2 = avail2 / ((size_t)NB * 4);
    if ((size_t)cap2 > maxc2) cap2 = (int)maxc2;

    hipMemsetAsync(gCnt, 0, (size_t)(16 + NB) * 4, stream);

    const int gagg2 = ((n + 1) / 2 + 3) / 4;
    const int ggemm = (n + 63) / 64;
    const int gsplitA = (E + SP_CHUNK - 1) / SP_CHUNK;
    const int gsplitBx = (capS + SP_CHUNK - 1) / SP_CHUNK;

    splitA_kernel<<<gsplitA + 20, 256, 0, stream>>>(ei, gCnt, buf1, E, capS, gsplitA,
                                                    W1, W2, W3, Wf1, Wf2, Wf3);
    splitB_kernel<<<dim3(gsplitBx, NS), 256, 0, stream>>>(gCnt, buf1, cnt2, buf2, capS,
                                                          cap2, NB);
    binBC_kernel<<<NB, 256, 0, stream>>>(cnt2, buf2, cnt, dinv, rowstart, colb, n,
                                         cap2);

    // layer 1: T(fp8) = dinv * (x @ W1) ; Hb(bf16) = relu(di*(sum T) + b1)
    gemm_mfma<128, 1, 1><<<ggemm, 256, 0, stream>>>(x, Wf1, dinv, T, n);
    agg_relu_128_fp8<<<gagg2, 256, 0, stream>>>((const uint32_t*)T, rowstart, cnt,
                                                colb, dinv, b1, (uint32_t*)Hb, n);
    // layer 2
    gemm_mfma<128, 0, 1><<<ggemm, 256, 0, stream>>>(Hb, Wf2, dinv, T, n);
    agg_relu_128_fp8<<<gagg2, 256, 0, stream>>>((const uint32_t*)T, rowstart, cnt,
                                                colb, dinv, b2, (uint32_t*)Hb, n);
    // layer 3: T(fp8, 64 cols) = dinv * (Hb @ W3) ; out = log_softmax(...)
    gemm_mfma<64, 0, 1><<<ggemm, 256, 0, stream>>>(Hb, Wf3, dinv, T, n);
    agg_lsm_64_fp8<<<gagg2, 256, 0, stream>>>((const uint32_t*)T, rowstart, cnt, colb,
                                              dinv, b3, out, n);
}

// Round 10
// 277.093 us; speedup vs baseline: 1.4784x; 1.0664x over previous
//
#include <hip/hip_runtime.h>
#include <stdint.h>
#include <math.h>

#define FIN 128

typedef __attribute__((ext_vector_type(8))) short short8v;
typedef __attribute__((ext_vector_type(4))) float float4v;
typedef __attribute__((ext_vector_type(2))) float float2v;

// ---------------- bf16 helpers ----------------
__device__ __forceinline__ uint32_t f2_to_bf2(float x, float y) {
    uint32_t r;
    asm("v_cvt_pk_bf16_f32 %0, %1, %2" : "=v"(r) : "v"(x), "v"(y));
    return r;
}
__device__ __forceinline__ unsigned short f_to_bf(float x) {
    union { float f; uint32_t i; } a;
    a.f = x;
    uint32_t u = a.i + 0x7FFF + ((a.i >> 16) & 1);
    return (unsigned short)(u >> 16);
}
// acc2[0..7] (+)= 16 fp8 decoded (packed adds)
__device__ __forceinline__ void acc16_fp8_pk(float2v* acc2, uint4 v) {
    uint32_t us[4] = {v.x, v.y, v.z, v.w};
#pragma unroll
    for (int q = 0; q < 4; ++q) {
        acc2[q * 2 + 0] += __builtin_amdgcn_cvt_pk_f32_fp8(us[q], false);
        acc2[q * 2 + 1] += __builtin_amdgcn_cvt_pk_f32_fp8(us[q], true);
    }
}

// DPP cross-lane move on the VALU pipe: quad_perm / row_ror.
// xor1 = quad_perm[1,0,3,2] = 0xB1 ; xor2 = quad_perm[2,3,0,1] = 0x4E
// ror4 = 0x124 ; ror8 = 0x128. Rotation-sum within the 16-lane ring is a
// valid all-lanes reduce over the rotated bit(s).
template <int CTRL>
__device__ __forceinline__ float dppmov(float x) {
    int i = __builtin_bit_cast(int, x);
    int r = __builtin_amdgcn_update_dpp(i, i, CTRL, 0xF, 0xF, false);
    return __builtin_bit_cast(float, r);
}
__device__ __forceinline__ float swz16f(float x) {
    int r = __builtin_amdgcn_ds_swizzle(__builtin_bit_cast(int, x), 0x401F);
    return __builtin_bit_cast(float, r);
}

__device__ __forceinline__ int edge_at(const void* ei, long long idx, int is32) {
    return is32 ? ((const int*)ei)[idx] : (int)((const long long*)ei)[idx];
}

// ---------------- Level-1 split (16 super-bins, dst>>13) + fused W-conv ----------
// record = (src<<13)|(dst&8191), 30 bits (requires n < 2^19; here n = 100000)
// Blocks [nA, nA+20) run the weight->fragment-ordered bf16 conversion instead.
#define SP_CHUNK 4096
__global__ __launch_bounds__(256) void splitA_kernel(
        const void* __restrict__ ei, int* __restrict__ gCnt,
        uint32_t* __restrict__ buf1, int E, int capS, int nA,
        const float* __restrict__ W1, const float* __restrict__ W2,
        const float* __restrict__ W3, unsigned short* __restrict__ Wf1,
        unsigned short* __restrict__ Wf2, unsigned short* __restrict__ Wf3) {
    __shared__ int hist[16];
    __shared__ int gbase[16];
    __shared__ int lflag;
    int t = threadIdx.x;
    if (blockIdx.x >= nA) {
        // ---- fused wconv ----
        int idx = (blockIdx.x - nA) * 256 + t;
        const float* W;
        unsigned short* Wf;
        int NCOL, base;
        if (idx < 2048)      { W = W1; Wf = Wf1; NCOL = 128; base = idx; }
        else if (idx < 4096) { W = W2; Wf = Wf2; NCOL = 128; base = idx - 2048; }
        else if (idx < 5120) { W = W3; Wf = Wf3; NCOL = 64;  base = idx - 4096; }
        else return;
        int f = base >> 6, l = base & 63;
        int ct = f >> 2, ks = f & 3;
        int nn = ct * 16 + (l & 15);
        int k0 = ks * 32 + (l >> 4) * 8;
        uint32_t pk[4];
#pragma unroll
        for (int j = 0; j < 4; ++j) {
            float a = W[(size_t)(k0 + 2 * j) * NCOL + nn];
            float b = W[(size_t)(k0 + 2 * j + 1) * NCOL + nn];
            pk[j] = f2_to_bf2(a, b);
        }
        ((uint4*)Wf)[base] = make_uint4(pk[0], pk[1], pk[2], pk[3]);
        return;
    }
    if (t < 16) hist[t] = 0;
    if (t == 0) lflag = 0;
    long long base = (long long)blockIdx.x * SP_CHUNK;
    __syncthreads();
    {
        long long e = base + t;
        if (e < E && ((const int*)ei)[2 * e + 1] != 0) atomicOr(&lflag, 1);
    }
    __syncthreads();
    int is32 = lflag;
    uint32_t lrec[16], rec[16];
#pragma unroll
    for (int j = 0; j < 16; ++j) {
        long long e = base + t + j * 256;
        if (e < E) {
            int s = edge_at(ei, e, is32);
            int d = edge_at(ei, (long long)E + e, is32);
            int b = d >> 13;
            int lofs = atomicAdd(&hist[b], 1);
            lrec[j] = ((uint32_t)lofs << 4) | (uint32_t)b;
            rec[j] = ((uint32_t)s << 13) | (uint32_t)(d & 8191);
        } else
            lrec[j] = 0xFFFFFFFFu;
    }
    __syncthreads();
    if (t < 16) gbase[t] = atomicAdd(&gCnt[t], hist[t]);
    __syncthreads();
#pragma unroll
    for (int j = 0; j < 16; ++j) {
        if (lrec[j] != 0xFFFFFFFFu) {
            int b = lrec[j] & 15;
            int pos = gbase[b] + (int)(lrec[j] >> 4);
            if (pos < capS) buf1[(size_t)b * capS + pos] = rec[j];
        }
    }
}

// ---------------- Level-2 split: 128 sub-bins, LDS counting sort ----------------
__global__ __launch_bounds__(256) void splitB_kernel(const int* __restrict__ gCnt,
                                                     const uint32_t* __restrict__ buf1,
                                                     int* __restrict__ cnt2,
                                                     uint32_t* __restrict__ buf2,
                                                     int capS, int cap2, int NB) {
    __shared__ int hist[128];
    __shared__ int sbase[128];
    __shared__ int gbase[128];
    __shared__ uint32_t ordrec[SP_CHUNK];
    __shared__ unsigned char ordsub[SP_CHUNK];
    int t = threadIdx.x;
    int s = blockIdx.y;
    if (t < 128) hist[t] = 0;
    __syncthreads();
    int m = gCnt[s];
    if (m > capS) m = capS;
    long long base = (long long)blockIdx.x * SP_CHUNK;
    uint32_t lrec[16], r32[16];
#pragma unroll
    for (int j = 0; j < 16; ++j) {
        long long i = base + t + j * 256;
        if (i < m) {
            uint32_t r = buf1[(size_t)s * capS + i];
            int d13 = (int)(r & 8191u);
            int sub = d13 >> 6;
            int lofs = atomicAdd(&hist[sub], 1);
            lrec[j] = ((uint32_t)lofs << 7) | (uint32_t)sub;
            r32[j] = ((r >> 13) << 6) | (uint32_t)(d13 & 63);
        } else
            lrec[j] = 0xFFFFFFFFu;
    }
    __syncthreads();
    if (t < 128) sbase[t] = hist[t];
    __syncthreads();
    for (int off = 1; off < 128; off <<= 1) {
        int v = 0;
        if (t < 128 && t >= off) v = sbase[t - off];
        __syncthreads();
        if (t < 128) sbase[t] += v;
        __syncthreads();
    }
    if (t < 128) {
        int g = s * 128 + t;
        gbase[t] = (g < NB && hist[t] > 0) ? atomicAdd(&cnt2[g], hist[t]) : 0;
        sbase[t] -= hist[t];  // exclusive scan
    }
    __syncthreads();
#pragma unroll
    for (int j = 0; j < 16; ++j) {
        if (lrec[j] != 0xFFFFFFFFu) {
            int sub = lrec[j] & 127;
            int pos = sbase[sub] + (int)(lrec[j] >> 7);
            ordrec[pos] = r32[j];
            ordsub[pos] = (unsigned char)sub;
        }
    }
    __syncthreads();
    int mloc = (int)(m - base);
    if (mloc > SP_CHUNK) mloc = SP_CHUNK;
    if (mloc < 0) mloc = 0;
    for (int i = t; i < mloc; i += 256) {
        int sub = ordsub[i];
        int gpos = gbase[sub] + (i - sbase[sub]);
        if (gpos < cap2) buf2[(size_t)(s * 128 + sub) * cap2 + gpos] = ordrec[i];
    }
}

// ---------------- merged: degree+dinv+rowstart + CSR scatter ----------------
__global__ __launch_bounds__(256) void binBC_kernel(const int* __restrict__ cnt2,
                                                    const uint32_t* __restrict__ buf2,
                                                    int* __restrict__ cnt,
                                                    float* __restrict__ dinv,
                                                    int* __restrict__ rowstart,
                                                    int* __restrict__ col,
                                                    int n, int cap2) {
    __shared__ int h[64];
    __shared__ int rowst[64];
    __shared__ int cur[64];
    __shared__ int sc[64];
    int bin = blockIdx.x;
    int t = threadIdx.x;
    if (t < 64) {
        h[t] = (bin * 64 + t < n) ? 1 : 0;  // self-loop pre-counted
        cur[t] = 1;                         // slot 0 reserved for self
    }
    __syncthreads();
    int m = cnt2[bin];
    if (m > cap2) m = cap2;
    const uint32_t* buf = buf2 + (size_t)bin * cap2;
    for (int i = t; i < m; i += 256) atomicAdd(&h[buf[i] & 63], 1);
    __syncthreads();
    int c = 0, pc = 0;
    if (t < 64) { c = h[t]; pc = (c + 7) & ~7; sc[t] = pc; }
    __syncthreads();
    for (int off = 1; off < 64; off <<= 1) {
        int v = 0;
        if (t < 64 && t >= off) v = sc[t - off];
        __syncthreads();
        if (t < 64) sc[t] += v;
        __syncthreads();
    }
    if (t < 64) {
        int node = bin * 64 + t;
        int base = bin * cap2;
        int st = base + sc[t] - pc;
        rowst[t] = st;
        if (node < n) {
            cnt[node] = c;
            dinv[node] = rsqrtf((float)c);
            rowstart[node] = st;
            col[st] = node;                       // self-loop entry
            for (int k = c; k < pc; ++k) col[st + k] = n;  // sentinel pad
        }
    }
    __syncthreads();
    for (int i = t; i < m; i += 256) {
        uint32_t rec = buf[i];
        int d6 = rec & 63;
        int off = atomicAdd(&cur[d6], 1);
        col[rowst[d6] + off] = (int)(rec >> 6);
    }
}

// ---------------- MFMA GEMM + dinv row-scale epilogue; OUT_FP8 packs e4m3 ----------
// Block 0 also zeroes the sentinel row (bytes [n*NCOL, n*NCOL+NCOL)).
template <int NCOL, int A_FP32, int OUT_FP8>
__global__ __launch_bounds__(256) void gemm_mfma(const void* __restrict__ Av,
                                                 const unsigned short* __restrict__ Wf,
                                                 const float* __restrict__ dinv,
                                                 void* __restrict__ Cv, int n) {
    __shared__ unsigned short lds[NCOL * 128];
    const int t = threadIdx.x;
    if (blockIdx.x == 0 && t < NCOL / 4)
        ((uint32_t*)Cv)[(size_t)n * (NCOL / 4) + t] = 0;
    for (int i = t; i < NCOL * 16; i += 256)
        ((uint4*)lds)[i] = ((const uint4*)Wf)[i];
    __syncthreads();

    const int wave = t >> 6, lane = t & 63;
    const int row0 = blockIdx.x * 64 + wave * 16;
    const int m = lane & 15, quad = lane >> 4;
    int arow = row0 + m;
    if (arow >= n) arow = n - 1;

    short8v a[4];
    if (A_FP32) {
        const float* A = (const float*)Av;
#pragma unroll
        for (int ks = 0; ks < 4; ++ks) {
            float4 lo = *(const float4*)(A + (size_t)arow * 128 + ks * 32 + quad * 8);
            float4 hi = *(const float4*)(A + (size_t)arow * 128 + ks * 32 + quad * 8 + 4);
            union { short8v v; uint32_t u[4]; } pk;
            pk.u[0] = f2_to_bf2(lo.x, lo.y);
            pk.u[1] = f2_to_bf2(lo.z, lo.w);
            pk.u[2] = f2_to_bf2(hi.x, hi.y);
            pk.u[3] = f2_to_bf2(hi.z, hi.w);
            a[ks] = pk.v;
        }
    } else {
        const unsigned short* A = (const unsigned short*)Av;
#pragma unroll
        for (int ks = 0; ks < 4; ++ks)
            a[ks] = *(const short8v*)(A + (size_t)arow * 128 + ks * 32 + quad * 8);
    }

    const int cr0 = row0 + quad * 4;
    float ds[4];
#pragma unroll
    for (int r = 0; r < 4; ++r) {
        int gr = cr0 + r;
        ds[r] = (gr < n) ? dinv[gr] : 0.0f;
    }
#pragma unroll
    for (int ct = 0; ct < NCOL / 16; ++ct) {
        float4v acc = {0.0f, 0.0f, 0.0f, 0.0f};
#pragma unroll
        for (int ks = 0; ks < 4; ++ks) {
            int f = ct * 4 + ks;
            short8v b = *(const short8v*)(lds + ((size_t)(f * 64 + lane)) * 8);
            acc = __builtin_amdgcn_mfma_f32_16x16x32_bf16(a[ks], b, acc, 0, 0, 0);
        }
#pragma unroll
        for (int r = 0; r < 4; ++r) {
            int gr = cr0 + r;
            if (gr < n) {
                float val = acc[r] * ds[r];
                if (OUT_FP8) {
                    int u = __builtin_amdgcn_cvt_pk_fp8_f32(val, val, 0, false);
                    ((unsigned char*)Cv)[(size_t)gr * NCOL + ct * 16 + m] =
                        (unsigned char)(u & 0xFF);
                } else {
                    ((unsigned short*)Cv)[(size_t)gr * NCOL + ct * 16 + m] = f_to_bf(val);
                }
            }
        }
    }
}

// ---------------- 2-node aggregation, 128 feats, fp8 T (128B rows) ----------------
// lane bits: j = b0-b2 (8 chunks x 16B, contiguous -> coalesced 128B rows),
// slot = b3-b4 (4 edge slots), sel = b5 (node).
// Straight-line 4-stage unconditional preload (8 gathers in flight): stages
// >= nit are index-masked to the sentinel zero row n (decoded 0.0 ->
// accumulate no-op). Branchless for deg <= 32; rare tail loop for deg > 32.
// NOTE (r8 lesson): a degM early-out branch doubles VGPR (28->48, occupancy
// 66->42%) and is a net loss — keep this straight-line.
// Slot reduce: row_ror:8 (bit3) + ds_swizzle xor16 (bit4).
__global__ __launch_bounds__(256) void agg_relu_128_fp8(
        const uint32_t* __restrict__ T8, const int* __restrict__ rowstart,
        const int* __restrict__ cnt, const int* __restrict__ col,
        const float* __restrict__ dinv, const float* __restrict__ bias,
        uint32_t* __restrict__ outHb, int n) {
    int wid = blockIdx.x * 4 + (threadIdx.x >> 6);
    int lane = threadIdx.x & 63;
    int j = lane & 7, slot = (lane >> 3) & 3, sel = lane >> 5;
    int nodeA = wid * 2;
    int node = nodeA + sel;
    if (nodeA >= n) return;
    bool valid = node < n;
    int nd = valid ? node : nodeA;
    int start = rowstart[nd];
    int c = cnt[nd];
    int nit = valid ? (((c + 7) & ~7) >> 3) : 0;   // stages of 8 edges

    float2v acc2[8];
#pragma unroll
    for (int k = 0; k < 8; ++k) acc2[k] = (float2v){0.0f, 0.0f};
    const uint4* T4 = (const uint4*)T8;
    int bp = start + slot;
    // ---- 4-stage preload: 8 col reads -> 8 masked selects -> 8 gathers ----
    int s00 = col[bp +  0], s01 = col[bp +  4];
    int s10 = col[bp +  8], s11 = col[bp + 12];
    int s20 = col[bp + 16], s21 = col[bp + 20];
    int s30 = col[bp + 24], s31 = col[bp + 28];
    s00 = (0 < nit) ? s00 : n;  s01 = (0 < nit) ? s01 : n;
    s10 = (1 < nit) ? s10 : n;  s11 = (1 < nit) ? s11 : n;
    s20 = (2 < nit) ? s20 : n;  s21 = (2 < nit) ? s21 : n;
    s30 = (3 < nit) ? s30 : n;  s31 = (3 < nit) ? s31 : n;
    uint4 v00 = T4[(size_t)s00 * 8 + j], v01 = T4[(size_t)s01 * 8 + j];
    uint4 v10 = T4[(size_t)s10 * 8 + j], v11 = T4[(size_t)s11 * 8 + j];
    uint4 v20 = T4[(size_t)s20 * 8 + j], v21 = T4[(size_t)s21 * 8 + j];
    uint4 v30 = T4[(size_t)s30 * 8 + j], v31 = T4[(size_t)s31 * 8 + j];
    acc16_fp8_pk(acc2, v00); acc16_fp8_pk(acc2, v01);
    acc16_fp8_pk(acc2, v10); acc16_fp8_pk(acc2, v11);
    acc16_fp8_pk(acc2, v20); acc16_fp8_pk(acc2, v21);
    acc16_fp8_pk(acc2, v30); acc16_fp8_pk(acc2, v31);
    // ---- rare tail (deg > 32) ----
    for (int s = 4; s < nit; ++s) {
        int a0 = col[bp + s * 8], a1 = col[bp + s * 8 + 4];
        uint4 w0 = T4[(size_t)a0 * 8 + j];
        uint4 w1 = T4[(size_t)a1 * 8 + j];
        acc16_fp8_pk(acc2, w0);
        acc16_fp8_pk(acc2, w1);
    }
    float* acc = (float*)acc2;
#pragma unroll
    for (int k = 0; k < 16; ++k) acc[k] += dppmov<0x128>(acc[k]);  // ror8 (bit3)
#pragma unroll
    for (int k = 0; k < 16; ++k) acc[k] += swz16f(acc[k]);         // xor16 (bit4)
    if (slot == 0 && valid) {
        float di = dinv[node];
        const float4* b4 = (const float4*)bias;
        float r[16];
#pragma unroll
        for (int q = 0; q < 4; ++q) {
            float4 bb = b4[j * 4 + q];
            r[q * 4 + 0] = fmaxf(di * acc[q * 4 + 0] + bb.x, 0.0f);
            r[q * 4 + 1] = fmaxf(di * acc[q * 4 + 1] + bb.y, 0.0f);
            r[q * 4 + 2] = fmaxf(di * acc[q * 4 + 2] + bb.z, 0.0f);
            r[q * 4 + 3] = fmaxf(di * acc[q * 4 + 3] + bb.w, 0.0f);
        }
        uint4 o0, o1;
        o0.x = f2_to_bf2(r[0], r[1]);   o0.y = f2_to_bf2(r[2], r[3]);
        o0.z = f2_to_bf2(r[4], r[5]);   o0.w = f2_to_bf2(r[6], r[7]);
        o1.x = f2_to_bf2(r[8], r[9]);   o1.y = f2_to_bf2(r[10], r[11]);
        o1.z = f2_to_bf2(r[12], r[13]); o1.w = f2_to_bf2(r[14], r[15]);
        *(uint4*)(outHb + (size_t)node * 64 + j * 8) = o0;
        *(uint4*)(outHb + (size_t)node * 64 + j * 8 + 4) = o1;
    }
}

// ---------------- 2-node aggregation, 64 feats fp8 (64B rows) + log_softmax --------
// lane bits: j = b0-b1 (4 chunks x 16B, contiguous 64B rows), slot = b2-b4
// (8 edge slots), sel = b5. Straight-line 4-stage preload (sentinel-masked)
// + rare tail loop. Slot reduce: ror4 + ror8 (bits 2,3) + swz16 (bit 4);
// softmax j-reduce: quad_perm xor1 + xor2 (bits 0,1).
__global__ __launch_bounds__(256) void agg_lsm_64_fp8(
        const uint32_t* __restrict__ T8, const int* __restrict__ rowstart,
        const int* __restrict__ cnt, const int* __restrict__ col,
        const float* __restrict__ dinv, const float* __restrict__ bias,
        float* __restrict__ out, int n) {
    int wid = blockIdx.x * 4 + (threadIdx.x >> 6);
    int lane = threadIdx.x & 63;
    int j = lane & 3, slot = (lane >> 2) & 7, sel = lane >> 5;
    int nodeA = wid * 2;
    int node = nodeA + sel;
    if (nodeA >= n) return;
    bool valid = node < n;
    int nd = valid ? node : nodeA;
    int start = rowstart[nd];
    int c = cnt[nd];
    int nit = valid ? (((c + 7) & ~7) >> 3) : 0;   // stages of 8 edges

    float2v acc2[8];
#pragma unroll
    for (int k = 0; k < 8; ++k) acc2[k] = (float2v){0.0f, 0.0f};
    const uint4* T4 = (const uint4*)T8;
    int bp = start + slot;
    int a0 = col[bp +  0];
    int a1 = col[bp +  8];
    int a2 = col[bp + 16];
    int a3 = col[bp + 24];
    a0 = (0 < nit) ? a0 : n;
    a1 = (1 < nit) ? a1 : n;
    a2 = (2 < nit) ? a2 : n;
    a3 = (3 < nit) ? a3 : n;
    uint4 v0 = T4[(size_t)a0 * 4 + j];
    uint4 v1 = T4[(size_t)a1 * 4 + j];
    uint4 v2 = T4[(size_t)a2 * 4 + j];
    uint4 v3 = T4[(size_t)a3 * 4 + j];
    acc16_fp8_pk(acc2, v0);
    acc16_fp8_pk(acc2, v1);
    acc16_fp8_pk(acc2, v2);
    acc16_fp8_pk(acc2, v3);
    for (int s = 4; s < nit; ++s) {
        int aa = col[bp + s * 8];
        uint4 w = T4[(size_t)aa * 4 + j];
        acc16_fp8_pk(acc2, w);
    }
    float* acc = (float*)acc2;
#pragma unroll
    for (int k = 0; k < 16; ++k) acc[k] += dppmov<0x124>(acc[k]);  // ror4 (bit2)
#pragma unroll
    for (int k = 0; k < 16; ++k) acc[k] += dppmov<0x128>(acc[k]);  // ror8 (bit3)
#pragma unroll
    for (int k = 0; k < 16; ++k) acc[k] += swz16f(acc[k]);         // xor16 (bit4)
    float di = dinv[nd];
    const float4* b4 = (const float4*)bias;
    float r[16];
#pragma unroll
    for (int q = 0; q < 4; ++q) {
        float4 bb = b4[j * 4 + q];
        r[q * 4 + 0] = di * acc[q * 4 + 0] + bb.x;
        r[q * 4 + 1] = di * acc[q * 4 + 1] + bb.y;
        r[q * 4 + 2] = di * acc[q * 4 + 2] + bb.z;
        r[q * 4 + 3] = di * acc[q * 4 + 3] + bb.w;
    }
    // log_softmax over 64 feats: 16 local + j-reduce over lane bits 0,1
    float m0 = fmaxf(fmaxf(r[0], r[1]), fmaxf(r[2], r[3]));
    float m1 = fmaxf(fmaxf(r[4], r[5]), fmaxf(r[6], r[7]));
    float m2 = fmaxf(fmaxf(r[8], r[9]), fmaxf(r[10], r[11]));
    float m3 = fmaxf(fmaxf(r[12], r[13]), fmaxf(r[14], r[15]));
    float m = fmaxf(fmaxf(m0, m1), fmaxf(m2, m3));
    m = fmaxf(m, dppmov<0xB1>(m));   // xor1
    m = fmaxf(m, dppmov<0x4E>(m));   // xor2
    float e0 = __expf(r[0] - m) + __expf(r[1] - m) + __expf(r[2] - m) +
               __expf(r[3] - m);
    float e1 = __expf(r[4] - m) + __expf(r[5] - m) + __expf(r[6] - m) +
               __expf(r[7] - m);
    float e2 = __expf(r[8] - m) + __expf(r[9] - m) + __expf(r[10] - m) +
               __expf(r[11] - m);
    float e3 = __expf(r[12] - m) + __expf(r[13] - m) + __expf(r[14] - m) +
               __expf(r[15] - m);
    float ss = (e0 + e1) + (e2 + e3);
    ss += dppmov<0xB1>(ss);
    ss += dppmov<0x4E>(ss);
    float lg = m + __logf(ss);
    if (slot == 0 && valid) {
#pragma unroll
        for (int q = 0; q < 4; ++q) {
            float4 o = make_float4(r[q * 4 + 0] - lg, r[q * 4 + 1] - lg,
                                   r[q * 4 + 2] - lg, r[q * 4 + 3] - lg);
            *(float4*)(out + (size_t)node * 64 + j * 16 + q * 4) = o;
        }
    }
}

// ---------------- launcher ----------------
extern "C" void kernel_launch(void* const* d_in, const int* in_sizes, int n_in,
                              void* d_out, int out_size, void* d_ws, size_t ws_size,
                              hipStream_t stream) {
    const float* x  = (const float*)d_in[0];
    const void*  ei = d_in[1];
    const float* W1 = (const float*)d_in[2];
    const float* b1 = (const float*)d_in[3];
    const float* W2 = (const float*)d_in[4];
    const float* b2 = (const float*)d_in[5];
    const float* W3 = (const float*)d_in[6];
    const float* b3 = (const float*)d_in[7];
    float* out = (float*)d_out;

    const int n = in_sizes[0] / FIN;       // 100000
    const int E = in_sizes[1] / 2;         // 1600000

    char* p = (char*)d_ws;
    auto carve = [&](size_t bytes) {
        char* q = p;
        p += (bytes + 255) & ~(size_t)255;
        return q;
    };
    const int NB = (n + 63) / 64;
    const int NS = (n + 8191) / 8192;

    long long meanS = (long long)E * 8192 / n;
    int capS = (int)(meanS + 8 * (long long)sqrt((double)meanS) + 1024);
    capS = (capS + 15) & ~15;
    long long mean2 = (long long)E * 64 / n;
    // + self-loops (64) + per-node x8 padding (<=448) + tail slack
    int cap2 = (int)(mean2 + 8 * (long long)sqrt((double)mean2) + 1152);
    cap2 = (cap2 + 15) & ~15;

    int*   cnt      = (int*)carve((size_t)n * 4);
    int*   rowstart = (int*)carve((size_t)n * 4);
    float* dinv     = (float*)carve((size_t)n * 4);
    int*   colb     = (int*)carve(((size_t)NB * cap2 + 4096) * 4);
    int*   gCnt     = (int*)carve((size_t)(16 + NB) * 4);
    int*   cnt2     = gCnt + 16;
    // T: fp8 n*128 + 256B sentinel zero-row; Hb bf16 n*128.
    size_t Tbytes = (size_t)n * 128 + 256;
    size_t Hbytes = (size_t)n * 128 * 2;
    char*  TH = carve(Tbytes + Hbytes);
    void*  T  = (void*)TH;
    unsigned short* Hb = (unsigned short*)(TH + Tbytes);
    unsigned short* Wf1 = (unsigned short*)carve(128 * 128 * 2);
    unsigned short* Wf2 = (unsigned short*)carve(128 * 128 * 2);
    unsigned short* Wf3 = (unsigned short*)carve(128 * 64 * 2);

    // split bufs alias the T+Hb region (free during preprocessing)
    size_t buf1B = ((size_t)NS * capS * 4 + 255) & ~(size_t)255;
    uint32_t* buf1 = (uint32_t*)TH;
    uint32_t* buf2 = (uint32_t*)(TH + buf1B);
    size_t avail2 = (Tbytes + Hbytes > buf1B) ? (Tbytes + Hbytes - buf1B) : 0;
    size_t maxc2 = avail2 / ((size_t)NB * 4);
    if ((size_t)cap2 > maxc2) cap2 = (int)maxc2;

    hipMemsetAsync(gCnt, 0, (size_t)(16 + NB) * 4, stream);

    const int gagg2 = ((n + 1) / 2 + 3) / 4;
    const int ggemm = (n + 63) / 64;
    const int gsplitA = (E + SP_CHUNK - 1) / SP_CHUNK;
    const int gsplitBx = (capS + SP_CHUNK - 1) / SP_CHUNK;

    splitA_kernel<<<gsplitA + 20, 256, 0, stream>>>(ei, gCnt, buf1, E, capS, gsplitA,
                                                    W1, W2, W3, Wf1, Wf2, Wf3);
    splitB_kernel<<<dim3(gsplitBx, NS), 256, 0, stream>>>(gCnt, buf1, cnt2, buf2, capS,
                                                          cap2, NB);
    binBC_kernel<<<NB, 256, 0, stream>>>(cnt2, buf2, cnt, dinv, rowstart, colb, n,
                                         cap2);

    // layer 1: T(fp8) = dinv * (x @ W1) ; Hb(bf16) = relu(di*(sum T) + b1)
    gemm_mfma<128, 1, 1><<<ggemm, 256, 0, stream>>>(x, Wf1, dinv, T, n);
    agg_relu_128_fp8<<<gagg2, 256, 0, stream>>>((const uint32_t*)T, rowstart, cnt,
                                                colb, dinv, b1, (uint32_t*)Hb, n);
    // layer 2
    gemm_mfma<128, 0, 1><<<ggemm, 256, 0, stream>>>(Hb, Wf2, dinv, T, n);
    agg_relu_128_fp8<<<gagg2, 256, 0, stream>>>((const uint32_t*)T, rowstart, cnt,
                                                colb, dinv, b2, (uint32_t*)Hb, n);
    // layer 3: T(fp8, 64 cols) = dinv * (Hb @ W3) ; out = log_softmax(...)
    gemm_mfma<64, 0, 1><<<ggemm, 256, 0, stream>>>(Hb, Wf3, dinv, T, n);
    agg_lsm_64_fp8<<<gagg2, 256, 0, stream>>>((const uint32_t*)T, rowstart, cnt, colb,
                                              dinv, b3, out, n);
}